// Round 9
// baseline (470.664 us; speedup 1.0000x reference)
//
#include <hip/hip_runtime.h>

#define N_NODES 8192
#define IN_F    256
#define OUT_F   128
#define ALPHA_S 0.2f

typedef __attribute__((ext_vector_type(8))) short  short8;
typedef __attribute__((ext_vector_type(4))) short  short4v;
typedef __attribute__((ext_vector_type(4))) float  floatx4;
typedef __attribute__((ext_vector_type(4))) int    intx4;
typedef __attribute__((ext_vector_type(4))) float  fx4;

static __device__ __forceinline__ short f2bf(float f) {
    union { float f; unsigned int i; } u; u.f = f;
    unsigned int r = u.i + 0x7FFFu + ((u.i >> 16) & 1u);  // RNE
    return (short)(r >> 16);
}

// ---------------------------------------------------------------------------
// k_wh: Wh = h @ W via bf16 MFMA -> WhT bf16 [OUT_F][N_NODES].
//       src/dst fp32-exact via q1=W@a1, q2=W@a2 folded into W staging.
// 256 blocks x 512 threads, 32 rows/block. (validated R5-R8; unchanged)
// ---------------------------------------------------------------------------
__global__ __launch_bounds__(512) void k_wh(
    const float* __restrict__ h,    // [N][IN_F] fp32
    const float* __restrict__ W,    // [IN_F][OUT_F] fp32
    const float* __restrict__ a,    // [2*OUT_F] fp32
    short* __restrict__ WhT,        // [OUT_F][N] bf16
    float* __restrict__ src,
    float* __restrict__ dst)
{
    __shared__ short Wt[OUT_F][IN_F + 8];
    __shared__ short htile[32][IN_F + 8];
    __shared__ float q1s[IN_F], q2s[IN_F];
    __shared__ short wh_t[OUT_F][40];

    const int t      = threadIdx.x;
    const int lane   = t & 63;
    const int wave   = t >> 6;
    const int r_base = blockIdx.x * 32;

#pragma unroll
    for (int rep = 0; rep < 4; ++rep) {
        const int idx = rep * 8192 + t * 16;
        const int k   = idx >> 7;
        const int f   = idx & 127;
        fx4 w0 = *(const fx4*)(W + idx);
        fx4 w1 = *(const fx4*)(W + idx + 4);
        fx4 w2 = *(const fx4*)(W + idx + 8);
        fx4 w3 = *(const fx4*)(W + idx + 12);
        fx4 a10 = *(const fx4*)(a + f);
        fx4 a11 = *(const fx4*)(a + f + 4);
        fx4 a12 = *(const fx4*)(a + f + 8);
        fx4 a13 = *(const fx4*)(a + f + 12);
        fx4 a20 = *(const fx4*)(a + OUT_F + f);
        fx4 a21 = *(const fx4*)(a + OUT_F + f + 4);
        fx4 a22 = *(const fx4*)(a + OUT_F + f + 8);
        fx4 a23 = *(const fx4*)(a + OUT_F + f + 12);
        float p1 = 0.f, p2 = 0.f;
#pragma unroll
        for (int e = 0; e < 4; ++e) {
            p1 = fmaf(w0[e], a10[e], p1); p2 = fmaf(w0[e], a20[e], p2);
            p1 = fmaf(w1[e], a11[e], p1); p2 = fmaf(w1[e], a21[e], p2);
            p1 = fmaf(w2[e], a12[e], p1); p2 = fmaf(w2[e], a22[e], p2);
            p1 = fmaf(w3[e], a13[e], p1); p2 = fmaf(w3[e], a23[e], p2);
        }
#pragma unroll
        for (int e = 0; e < 4; ++e) {
            Wt[f + e][k]      = f2bf(w0[e]);
            Wt[f + 4 + e][k]  = f2bf(w1[e]);
            Wt[f + 8 + e][k]  = f2bf(w2[e]);
            Wt[f + 12 + e][k] = f2bf(w3[e]);
        }
#pragma unroll
        for (int m = 1; m < 8; m <<= 1) {
            p1 += __shfl_xor(p1, m, 64);
            p2 += __shfl_xor(p2, m, 64);
        }
        if ((t & 7) == 0) { q1s[k] = p1; q2s[k] = p2; }
    }

    const int r0   = t >> 4;
    const int fgrp = t & 15;
    const int k0   = fgrp * 16;
    fx4 h0, h1, h2, h3;
    {
        const float* hp = h + (size_t)(r_base + r0) * IN_F + k0;
        h0 = *(const fx4*)hp; h1 = *(const fx4*)(hp + 4);
        h2 = *(const fx4*)(hp + 8); h3 = *(const fx4*)(hp + 12);
        short8 b0, b1;
#pragma unroll
        for (int e = 0; e < 4; ++e) {
            b0[e]     = f2bf(h0[e]); b0[4 + e] = f2bf(h1[e]);
            b1[e]     = f2bf(h2[e]); b1[4 + e] = f2bf(h3[e]);
        }
        *(short8*)&htile[r0][k0]     = b0;
        *(short8*)&htile[r0][k0 + 8] = b1;
    }
    __syncthreads();

    {
        float sp = 0.f, dp = 0.f;
#pragma unroll
        for (int e = 0; e < 4; ++e) {
            sp = fmaf(h0[e], q1s[k0 + e], sp);      dp = fmaf(h0[e], q2s[k0 + e], dp);
            sp = fmaf(h1[e], q1s[k0 + 4 + e], sp);  dp = fmaf(h1[e], q2s[k0 + 4 + e], dp);
            sp = fmaf(h2[e], q1s[k0 + 8 + e], sp);  dp = fmaf(h2[e], q2s[k0 + 8 + e], dp);
            sp = fmaf(h3[e], q1s[k0 + 12 + e], sp); dp = fmaf(h3[e], q2s[k0 + 12 + e], dp);
        }
#pragma unroll
        for (int m = 1; m < 16; m <<= 1) {
            sp += __shfl_xor(sp, m, 64);
            dp += __shfl_xor(dp, m, 64);
        }
        if (fgrp == 0) { src[r_base + r0] = sp; dst[r_base + r0] = dp; }
    }

    const int ln15 = lane & 15;
    const int q    = lane >> 4;
    const int f0   = wave * 16;
    floatx4 c0 = {0.f, 0.f, 0.f, 0.f};
    floatx4 c1 = {0.f, 0.f, 0.f, 0.f};
#pragma unroll
    for (int s = 0; s < 8; ++s) {
        short8 bf  = *(const short8*)&Wt[f0 + ln15][s * 32 + q * 8];
        short8 a0f = *(const short8*)&htile[ln15][s * 32 + q * 8];
        short8 a1f = *(const short8*)&htile[16 + ln15][s * 32 + q * 8];
        c0 = __builtin_amdgcn_mfma_f32_16x16x32_bf16(a0f, bf, c0, 0, 0, 0);
        c1 = __builtin_amdgcn_mfma_f32_16x16x32_bf16(a1f, bf, c1, 0, 0, 0);
    }
    {
        short4v p0, p1;
#pragma unroll
        for (int r = 0; r < 4; ++r) { p0[r] = f2bf(c0[r]); p1[r] = f2bf(c1[r]); }
        *(short4v*)&wh_t[f0 + ln15][q * 4]      = p0;
        *(short4v*)&wh_t[f0 + ln15][16 + q * 4] = p1;
    }
    __syncthreads();
    {
        const int f    = t >> 2;
        const int half = t & 3;
        *(short8*)(WhT + (size_t)f * N_NODES + r_base + half * 8) =
            *(const short8*)&wh_t[f][half * 8];
    }
}

// ---------------------------------------------------------------------------
// k_attn: BARRIER-FREE. Each wave owns 16 rows x 1024-j chunk x all 128 f.
// A-fragments (exp weights) built in registers per lane (A[m=lane&15]
// [k=quad*8+j] layout), adj prefetched one step ahead -- no __syncthreads,
// so the vmcnt(0) barrier-drain of R4-R8 is gone. Denominator via per-wave
// ones-MFMA (exactly paired bf16 weights). Plain partial stores, no atomics.
// grid 1024 (= 128 rowgroups x 8 j-chunks) x 256 threads (4 waves).
// ---------------------------------------------------------------------------
#define JSPLIT 8
#define JCH    (N_NODES / JSPLIT)   // 1024
#define SJ     64                   // j per step (2 MFMA k-frags)
#define NSTEP  (JCH / SJ)           // 16

__global__ __launch_bounds__(256, 4) void k_attn(
    const int*   __restrict__ adj,    // [N][N] int32
    const short* __restrict__ WhT,    // [OUT_F][N] bf16
    const float* __restrict__ src,
    const float* __restrict__ dstv,
    float* __restrict__ numer_part,   // [8][N][OUT_F] fp32
    float* __restrict__ denom_part)   // [8][N] fp32
{
    const int t    = threadIdx.x;
    const int lane = t & 63;
    const int wave = t >> 6;              // 0..3
    const int rg   = blockIdx.x >> 3;     // 0..127
    const int jc   = blockIdx.x & 7;      // 0..7
    const int r0w  = rg * 64 + wave * 16;
    const int jb   = jc * JCH;

    const int ln15 = lane & 15;
    const int q    = lane >> 4;           // 0..3

    const float srow = src[r0w + ln15];
    const int*   ab = adj  + (size_t)(r0w + ln15) * N_NODES + jb + q * 8;
    const float* db = dstv + jb + q * 8;
    const short* bb = WhT + (size_t)ln15 * N_NODES + jb + q * 8;

    floatx4 acc[8];
#pragma unroll
    for (int ft = 0; ft < 8; ++ft) acc[ft] = (floatx4){0.f, 0.f, 0.f, 0.f};
    floatx4 dacc = {0.f, 0.f, 0.f, 0.f};
    short8 ones;
#pragma unroll
    for (int j = 0; j < 8; ++j) ones[j] = (short)0x3F80;  // bf16 1.0

    // prefetch step 0 adj (4x intx4 = 64 B/lane in flight)
    intx4 m0 = *(const intx4*)(ab);
    intx4 m1 = *(const intx4*)(ab + 4);
    intx4 m2 = *(const intx4*)(ab + 32);
    intx4 m3 = *(const intx4*)(ab + 36);

    for (int s = 0; s < NSTEP; ++s) {
        const int off = s * SJ;
        intx4 c0 = m0, c1 = m1, c2 = m2, c3 = m3;
        if (s + 1 < NSTEP) {              // issue next step's adj stream early
            const int o2 = off + SJ;
            m0 = *(const intx4*)(ab + o2);
            m1 = *(const intx4*)(ab + o2 + 4);
            m2 = *(const intx4*)(ab + o2 + 32);
            m3 = *(const intx4*)(ab + o2 + 36);
        }
        fx4 d0 = *(const fx4*)(db + off);
        fx4 d1 = *(const fx4*)(db + off + 4);
        fx4 d2 = *(const fx4*)(db + off + 32);
        fx4 d3 = *(const fx4*)(db + off + 36);

        short8 A0, A1;
#pragma unroll
        for (int e = 0; e < 4; ++e) {
            float x, l;
            x = srow + d0[e]; l = fmaxf(x, ALPHA_S * x);
            A0[e]     = (c0[e] > 0) ? f2bf(__expf(l)) : (short)0;
            x = srow + d1[e]; l = fmaxf(x, ALPHA_S * x);
            A0[4 + e] = (c1[e] > 0) ? f2bf(__expf(l)) : (short)0;
            x = srow + d2[e]; l = fmaxf(x, ALPHA_S * x);
            A1[e]     = (c2[e] > 0) ? f2bf(__expf(l)) : (short)0;
            x = srow + d3[e]; l = fmaxf(x, ALPHA_S * x);
            A1[4 + e] = (c3[e] > 0) ? f2bf(__expf(l)) : (short)0;
        }

        dacc = __builtin_amdgcn_mfma_f32_16x16x32_bf16(A0, ones, dacc, 0, 0, 0);
        dacc = __builtin_amdgcn_mfma_f32_16x16x32_bf16(A1, ones, dacc, 0, 0, 0);

#pragma unroll
        for (int ft = 0; ft < 8; ++ft) {
            const short* bp = bb + (size_t)ft * 16 * N_NODES + off;
            short8 B0 = *(const short8*)bp;
            short8 B1 = *(const short8*)(bp + 32);
            acc[ft] = __builtin_amdgcn_mfma_f32_16x16x32_bf16(A0, B0, acc[ft], 0, 0, 0);
            acc[ft] = __builtin_amdgcn_mfma_f32_16x16x32_bf16(A1, B1, acc[ft], 0, 0, 0);
        }
    }

    // epilogue: plain partial stores. C-layout: row = q*4+r, col(f) = ln15.
    float* np = numer_part + ((size_t)jc * N_NODES + r0w) * OUT_F;
#pragma unroll
    for (int ft = 0; ft < 8; ++ft)
#pragma unroll
        for (int r = 0; r < 4; ++r)
            np[(size_t)(q * 4 + r) * OUT_F + ft * 16 + ln15] = acc[ft][r];
    if (ln15 == 0) {
        float* dp = denom_part + (size_t)jc * N_NODES + r0w;
#pragma unroll
        for (int r = 0; r < 4; ++r) dp[q * 4 + r] = dacc[r];
    }
}

// ---------------------------------------------------------------------------
// k_final: out = ELU( (sum_jc numer_part) / (sum_jc denom_part) ).
// denom==0 guard kept as diagnostic (inert k_attn shows absmax~0.97).
// ---------------------------------------------------------------------------
__global__ void k_final(const float* __restrict__ numer_part,
                        const float* __restrict__ denom_part,
                        float* __restrict__ out) {
    const int idx = blockIdx.x * 256 + threadIdx.x;   // grid 4096
    const int row = idx >> 7;
    float v = 0.f, dn = 0.f;
#pragma unroll
    for (int jc = 0; jc < JSPLIT; ++jc) {
        v  += numer_part[(size_t)jc * N_NODES * OUT_F + idx];
        dn += denom_part[(size_t)jc * N_NODES + row];
    }
    v = (dn != 0.f) ? (v / dn) : 0.f;
    v = v > 0.f ? v : (__expf(v) - 1.f);
    out[idx] = v;
}

// ---------------------------------------------------------------------------
extern "C" void kernel_launch(void* const* d_in, const int* in_sizes, int n_in,
                              void* d_out, int out_size, void* d_ws, size_t ws_size,
                              hipStream_t stream) {
    const float* h   = (const float*)d_in[0];   // fp32 [8192][256]
    const int*   adj = (const int*)d_in[1];     // int32 [8192][8192]
    const float* W   = (const float*)d_in[2];   // fp32 [256][128]
    const float* a   = (const float*)d_in[3];   // fp32 [256]
    float* out = (float*)d_out;                 // fp32 [8192][128]

    char*  ws         = (char*)d_ws;
    float* denom_part = (float*)ws;                             // 8*8192*4 = 256 KB
    short* WhT        = (short*)(ws + (256 << 10));             // 2 MB
    float* src        = (float*)(ws + (256 << 10) + (2 << 20)); // 32 KB
    float* dst        = src + N_NODES;                          // 32 KB
    float* numer_part = (float*)(ws + (4 << 20));               // 32 MB

    k_wh   <<<256, 512, 0, stream>>>(h, W, a, WhT, src, dst);
    k_attn <<<1024, 256, 0, stream>>>(adj, WhT, src, dst, numer_part, denom_part);
    k_final<<<4096, 256, 0, stream>>>(numer_part, denom_part, out);
}

// Round 10
// 413.430 us; speedup vs baseline: 1.1384x; 1.1384x over previous
//
#include <hip/hip_runtime.h>

#define N_NODES 8192
#define IN_F    256
#define OUT_F   128
#define ALPHA_S 0.2f

typedef __attribute__((ext_vector_type(8))) short  short8;
typedef __attribute__((ext_vector_type(4))) short  short4v;
typedef __attribute__((ext_vector_type(4))) float  floatx4;
typedef __attribute__((ext_vector_type(4))) int    intx4;
typedef __attribute__((ext_vector_type(4))) float  fx4;

static __device__ __forceinline__ short f2bf(float f) {
    union { float f; unsigned int i; } u; u.f = f;
    unsigned int r = u.i + 0x7FFFu + ((u.i >> 16) & 1u);  // RNE
    return (short)(r >> 16);
}

// ---------------------------------------------------------------------------
// k_wh: Wh = h @ W via bf16 MFMA. Output now in FRAGMENT-MAJOR layout:
//   WhB[jblk=node/32][ft=f/16][lane][8]  (lane = (q=j8,n=f15): value =
//   Wh[jblk*32 + q*8 + e][ft*16 + n])  -> k_attn B-loads are 1 coalesced
//   dwordx4 per fragment. src/dst fp32-exact via q1/q2 folded into staging.
// 256 blocks x 512 threads, 32 nodes/block. (core validated R5-R9)
// ---------------------------------------------------------------------------
__global__ __launch_bounds__(512) void k_wh(
    const float* __restrict__ h,    // [N][IN_F] fp32
    const float* __restrict__ W,    // [IN_F][OUT_F] fp32
    const float* __restrict__ a,    // [2*OUT_F] fp32
    short* __restrict__ WhB,        // [N/32][8][64][8] bf16 (2 MB)
    float* __restrict__ src,
    float* __restrict__ dst)
{
    __shared__ short Wt[OUT_F][IN_F + 8];
    __shared__ short htile[32][IN_F + 8];
    __shared__ float q1s[IN_F], q2s[IN_F];
    __shared__ short wh_t[OUT_F][40];   // [f][node_local]

    const int t      = threadIdx.x;
    const int lane   = t & 63;
    const int wave   = t >> 6;
    const int r_base = blockIdx.x * 32;

#pragma unroll
    for (int rep = 0; rep < 4; ++rep) {
        const int idx = rep * 8192 + t * 16;
        const int k   = idx >> 7;
        const int f   = idx & 127;
        fx4 w0 = *(const fx4*)(W + idx);
        fx4 w1 = *(const fx4*)(W + idx + 4);
        fx4 w2 = *(const fx4*)(W + idx + 8);
        fx4 w3 = *(const fx4*)(W + idx + 12);
        fx4 a10 = *(const fx4*)(a + f);
        fx4 a11 = *(const fx4*)(a + f + 4);
        fx4 a12 = *(const fx4*)(a + f + 8);
        fx4 a13 = *(const fx4*)(a + f + 12);
        fx4 a20 = *(const fx4*)(a + OUT_F + f);
        fx4 a21 = *(const fx4*)(a + OUT_F + f + 4);
        fx4 a22 = *(const fx4*)(a + OUT_F + f + 8);
        fx4 a23 = *(const fx4*)(a + OUT_F + f + 12);
        float p1 = 0.f, p2 = 0.f;
#pragma unroll
        for (int e = 0; e < 4; ++e) {
            p1 = fmaf(w0[e], a10[e], p1); p2 = fmaf(w0[e], a20[e], p2);
            p1 = fmaf(w1[e], a11[e], p1); p2 = fmaf(w1[e], a21[e], p2);
            p1 = fmaf(w2[e], a12[e], p1); p2 = fmaf(w2[e], a22[e], p2);
            p1 = fmaf(w3[e], a13[e], p1); p2 = fmaf(w3[e], a23[e], p2);
        }
#pragma unroll
        for (int e = 0; e < 4; ++e) {
            Wt[f + e][k]      = f2bf(w0[e]);
            Wt[f + 4 + e][k]  = f2bf(w1[e]);
            Wt[f + 8 + e][k]  = f2bf(w2[e]);
            Wt[f + 12 + e][k] = f2bf(w3[e]);
        }
#pragma unroll
        for (int m = 1; m < 8; m <<= 1) {
            p1 += __shfl_xor(p1, m, 64);
            p2 += __shfl_xor(p2, m, 64);
        }
        if ((t & 7) == 0) { q1s[k] = p1; q2s[k] = p2; }
    }

    const int r0   = t >> 4;
    const int fgrp = t & 15;
    const int k0   = fgrp * 16;
    fx4 h0, h1, h2, h3;
    {
        const float* hp = h + (size_t)(r_base + r0) * IN_F + k0;
        h0 = *(const fx4*)hp; h1 = *(const fx4*)(hp + 4);
        h2 = *(const fx4*)(hp + 8); h3 = *(const fx4*)(hp + 12);
        short8 b0, b1;
#pragma unroll
        for (int e = 0; e < 4; ++e) {
            b0[e]     = f2bf(h0[e]); b0[4 + e] = f2bf(h1[e]);
            b1[e]     = f2bf(h2[e]); b1[4 + e] = f2bf(h3[e]);
        }
        *(short8*)&htile[r0][k0]     = b0;
        *(short8*)&htile[r0][k0 + 8] = b1;
    }
    __syncthreads();

    {
        float sp = 0.f, dp = 0.f;
#pragma unroll
        for (int e = 0; e < 4; ++e) {
            sp = fmaf(h0[e], q1s[k0 + e], sp);      dp = fmaf(h0[e], q2s[k0 + e], dp);
            sp = fmaf(h1[e], q1s[k0 + 4 + e], sp);  dp = fmaf(h1[e], q2s[k0 + 4 + e], dp);
            sp = fmaf(h2[e], q1s[k0 + 8 + e], sp);  dp = fmaf(h2[e], q2s[k0 + 8 + e], dp);
            sp = fmaf(h3[e], q1s[k0 + 12 + e], sp); dp = fmaf(h3[e], q2s[k0 + 12 + e], dp);
        }
#pragma unroll
        for (int m = 1; m < 16; m <<= 1) {
            sp += __shfl_xor(sp, m, 64);
            dp += __shfl_xor(dp, m, 64);
        }
        if (fgrp == 0) { src[r_base + r0] = sp; dst[r_base + r0] = dp; }
    }

    const int ln15 = lane & 15;
    const int q    = lane >> 4;
    const int f0   = wave * 16;
    floatx4 c0 = {0.f, 0.f, 0.f, 0.f};
    floatx4 c1 = {0.f, 0.f, 0.f, 0.f};
#pragma unroll
    for (int s = 0; s < 8; ++s) {
        short8 bf  = *(const short8*)&Wt[f0 + ln15][s * 32 + q * 8];
        short8 a0f = *(const short8*)&htile[ln15][s * 32 + q * 8];
        short8 a1f = *(const short8*)&htile[16 + ln15][s * 32 + q * 8];
        c0 = __builtin_amdgcn_mfma_f32_16x16x32_bf16(a0f, bf, c0, 0, 0, 0);
        c1 = __builtin_amdgcn_mfma_f32_16x16x32_bf16(a1f, bf, c1, 0, 0, 0);
    }
    {
        short4v p0, p1;
#pragma unroll
        for (int r = 0; r < 4; ++r) { p0[r] = f2bf(c0[r]); p1[r] = f2bf(c1[r]); }
        *(short4v*)&wh_t[f0 + ln15][q * 4]      = p0;
        *(short4v*)&wh_t[f0 + ln15][16 + q * 4] = p1;
    }
    __syncthreads();
    {   // fragment-major store: thread t -> (ft = t>>6, frag-lane l2 = t&63)
        const int ft2 = t >> 6;
        const int l2  = t & 63;
        const int n2  = l2 & 15;
        const int q2  = l2 >> 4;
        short8 v = *(const short8*)&wh_t[ft2 * 16 + n2][q2 * 8];
        *(short8*)(WhB + (((size_t)blockIdx.x * 8 + ft2) * 64 + l2) * 8) = v;
    }
}

// ---------------------------------------------------------------------------
// k_attn: wave-independent, explicit 2-deep software pipeline.
// Wave = 16 rows x 1024-j chunk x all 128 f. B-frags from fragment-major WhB
// (1 coalesced dwordx4 each). Distinct register sets (M0/B0 vs M1/B1) so the
// compiler keeps a full step in flight (fine-grained vmcnt, no drain).
// dst chunk preloaded to LDS once (intra-quad broadcast reads, conflict-free).
// grid 1024 (= 128 rowgroups x 8 j-chunks) x 256 threads (4 waves).
// ---------------------------------------------------------------------------
#define JSPLIT 8
#define JCH    (N_NODES / JSPLIT)   // 1024
#define SJ     64                   // j per step (2 jblks of 32)
#define NSTEP  (JCH / SJ)           // 16

__global__ __launch_bounds__(256, 2) void k_attn(
    const int*   __restrict__ adj,    // [N][N] int32
    const short* __restrict__ WhB,    // [N/32][8][64][8] bf16
    const float* __restrict__ src,
    const float* __restrict__ dstv,
    float* __restrict__ numer_part,   // [8][N][OUT_F] fp32
    float* __restrict__ denom_part)   // [8][N] fp32
{
    __shared__ float dlds[JCH];       // 4 KB

    const int t    = threadIdx.x;
    const int lane = t & 63;
    const int wave = t >> 6;              // 0..3
    const int rg   = blockIdx.x >> 3;     // 0..127
    const int jc   = blockIdx.x & 7;      // 0..7
    const int r0w  = rg * 64 + wave * 16;
    const int jb   = jc * JCH;

    const int ln15 = lane & 15;
    const int q    = lane >> 4;           // 0..3

    // stage dst chunk to LDS (once)
    *(fx4*)&dlds[t * 4] = *(const fx4*)(dstv + jb + t * 4);
    __syncthreads();

    const float srow = src[r0w + ln15];
    const int*   ab = adj + (size_t)(r0w + ln15) * N_NODES + jb + q * 8;
    const short* wb = WhB + (size_t)(jc * 32) * 4096 + lane * 8;  // 4096 shorts/jblk

    floatx4 acc[8];
#pragma unroll
    for (int ft = 0; ft < 8; ++ft) acc[ft] = (floatx4){0.f, 0.f, 0.f, 0.f};
    floatx4 dacc = {0.f, 0.f, 0.f, 0.f};
    short8 ones;
#pragma unroll
    for (int j = 0; j < 8; ++j) ones[j] = (short)0x3F80;  // bf16 1.0

    intx4  M0[4], M1[4];
    short8 B0[16], B1[16];

    auto loadstep = [&](int s, intx4* M, short8* B) {
        const int off = s * SJ;
        M[0] = *(const intx4*)(ab + off);
        M[1] = *(const intx4*)(ab + off + 4);
        M[2] = *(const intx4*)(ab + off + 32);
        M[3] = *(const intx4*)(ab + off + 36);
        const short* bs = wb + (size_t)(2 * s) * 4096;
#pragma unroll
        for (int ft = 0; ft < 8; ++ft) {
            B[2 * ft]     = *(const short8*)(bs + ft * 512);
            B[2 * ft + 1] = *(const short8*)(bs + 4096 + ft * 512);
        }
    };

    auto compute = [&](int s, const intx4* M, const short8* B) {
        const int off = s * SJ;
        fx4 d0 = *(const fx4*)&dlds[off + q * 8];
        fx4 d1 = *(const fx4*)&dlds[off + q * 8 + 4];
        fx4 d2 = *(const fx4*)&dlds[off + 32 + q * 8];
        fx4 d3 = *(const fx4*)&dlds[off + 32 + q * 8 + 4];
        short8 A0, A1;
#pragma unroll
        for (int e = 0; e < 4; ++e) {
            float x, l;
            x = srow + d0[e]; l = fmaxf(x, ALPHA_S * x);
            A0[e]     = (M[0][e] > 0) ? f2bf(__expf(l)) : (short)0;
            x = srow + d1[e]; l = fmaxf(x, ALPHA_S * x);
            A0[4 + e] = (M[1][e] > 0) ? f2bf(__expf(l)) : (short)0;
            x = srow + d2[e]; l = fmaxf(x, ALPHA_S * x);
            A1[e]     = (M[2][e] > 0) ? f2bf(__expf(l)) : (short)0;
            x = srow + d3[e]; l = fmaxf(x, ALPHA_S * x);
            A1[4 + e] = (M[3][e] > 0) ? f2bf(__expf(l)) : (short)0;
        }
        dacc = __builtin_amdgcn_mfma_f32_16x16x32_bf16(A0, ones, dacc, 0, 0, 0);
        dacc = __builtin_amdgcn_mfma_f32_16x16x32_bf16(A1, ones, dacc, 0, 0, 0);
#pragma unroll
        for (int ft = 0; ft < 8; ++ft) {
            acc[ft] = __builtin_amdgcn_mfma_f32_16x16x32_bf16(A0, B[2 * ft],     acc[ft], 0, 0, 0);
            acc[ft] = __builtin_amdgcn_mfma_f32_16x16x32_bf16(A1, B[2 * ft + 1], acc[ft], 0, 0, 0);
        }
    };

    loadstep(0, M0, B0);
    for (int s = 0; s < NSTEP; s += 2) {
        if (s + 1 < NSTEP) loadstep(s + 1, M1, B1);
        compute(s, M0, B0);
        if (s + 2 < NSTEP) loadstep(s + 2, M0, B0);
        if (s + 1 < NSTEP) compute(s + 1, M1, B1);
    }

    // epilogue: plain partial stores. C-layout: row = q*4+r, col f = ft*16+ln15.
    float* np = numer_part + ((size_t)jc * N_NODES + r0w) * OUT_F;
#pragma unroll
    for (int ft = 0; ft < 8; ++ft)
#pragma unroll
        for (int r = 0; r < 4; ++r)
            np[(size_t)(q * 4 + r) * OUT_F + ft * 16 + ln15] = acc[ft][r];
    if (ln15 == 0) {
        float* dp = denom_part + (size_t)jc * N_NODES + r0w;
#pragma unroll
        for (int r = 0; r < 4; ++r) dp[q * 4 + r] = dacc[r];
    }
}

// ---------------------------------------------------------------------------
// k_final: out = ELU( (sum_jc numer_part) / (sum_jc denom_part) ).
// denom==0 guard kept as diagnostic (inert k_attn shows absmax~0.97).
// ---------------------------------------------------------------------------
__global__ void k_final(const float* __restrict__ numer_part,
                        const float* __restrict__ denom_part,
                        float* __restrict__ out) {
    const int idx = blockIdx.x * 256 + threadIdx.x;   // grid 4096
    const int row = idx >> 7;
    float v = 0.f, dn = 0.f;
#pragma unroll
    for (int jc = 0; jc < JSPLIT; ++jc) {
        v  += numer_part[(size_t)jc * N_NODES * OUT_F + idx];
        dn += denom_part[(size_t)jc * N_NODES + row];
    }
    v = (dn != 0.f) ? (v / dn) : 0.f;
    v = v > 0.f ? v : (__expf(v) - 1.f);
    out[idx] = v;
}

// ---------------------------------------------------------------------------
extern "C" void kernel_launch(void* const* d_in, const int* in_sizes, int n_in,
                              void* d_out, int out_size, void* d_ws, size_t ws_size,
                              hipStream_t stream) {
    const float* h   = (const float*)d_in[0];   // fp32 [8192][256]
    const int*   adj = (const int*)d_in[1];     // int32 [8192][8192]
    const float* W   = (const float*)d_in[2];   // fp32 [256][128]
    const float* a   = (const float*)d_in[3];   // fp32 [256]
    float* out = (float*)d_out;                 // fp32 [8192][128]

    char*  ws         = (char*)d_ws;
    float* denom_part = (float*)ws;                             // 256 KB
    short* WhB        = (short*)(ws + (256 << 10));             // 2 MB
    float* src        = (float*)(ws + (256 << 10) + (2 << 20)); // 32 KB
    float* dst        = src + N_NODES;                          // 32 KB
    float* numer_part = (float*)(ws + (4 << 20));               // 32 MB

    k_wh   <<<256, 512, 0, stream>>>(h, W, a, WhB, src, dst);
    k_attn <<<1024, 256, 0, stream>>>(adj, WhB, src, dst, numer_part, denom_part);
    k_final<<<4096, 256, 0, stream>>>(numer_part, denom_part, out);
}